// Round 10
// baseline (79.290 us; speedup 1.0000x reference)
//
#include <hip/hip_runtime.h>

#define DD 192
#define HH 224
#define WW 192
#define HWN (HH*WW)              // 43008
#define PLANE ((size_t)DD*HWN)   // 8257536
#define DSEG 16                  // d outputs per kA block
#define NSTEP (DSEG + 8)         // 24 d-steps per block
#define HS 28                    // h outputs per kB block
#define NHS 8                    // 8 * 28 = 224
#define NPART (DD*NHS)           // 1536

// ---------------- kA: products + W-tap + D-tap, barrier-free, 2-deep ------
// Round-6 passing structure (DSEG=16, F4/F1 stores); ONLY change: prefetch
// depth 1 -> 2. Step s: issue loads for slab s+2 into the free reg set ->
// compute step s from buf(s&1) -> ds_write slab s+1 (loaded at s-1) into
// buf(s&1 ^ 1). Even s: issue->setB, write setA; odd s: issue->setA,
// write setB. Prologue: slab0 -> buf0 direct, slab1 -> setA.
__global__ __launch_bounds__(192) void kA(
    const float* __restrict__ I, const float* __restrict__ J,
    float4* __restrict__ F4, float* __restrict__ F1,
    int chunk_base, int chunk)
{
    const int h  = blockIdx.x;                 // 0..223
    const int d0 = chunk_base + blockIdx.y * DSEG;
    const int wv = threadIdx.x >> 6;           // 0..2
    const int l  = threadIdx.x & 63;
    const int w0 = wv << 6;

    __shared__ float stg[3][2][2][72];         // [wave][buf][field][slot]
    float (*st)[2][72] = stg[wv];              // wave-private view

    // zero both buffers once (pads stay zero; masked lanes never write them)
#pragma unroll
    for (int b = 0; b < 2; ++b) {
        st[b][0][l] = 0.f; st[b][1][l] = 0.f;
        if (l < 8) { st[b][0][64 + l] = 0.f; st[b][1][64 + l] = 0.f; }
    }

    const size_t rowb = (size_t)h * WW;
    const int  cm = w0 - 4 + l;                // main staged col -> slot l
    const int  ch = w0 + 60 + l;               // halo staged col -> slot 64+l
    const bool vm = (cm >= 0) && (cm < WW);
    const bool vh = (l < 8) && (ch < WW);

    float r0[9], r1[9], r2[9], r3[9], r4[9];
    float S0=0.f,S1=0.f,S2=0.f,S3=0.f,S4=0.f;
#pragma unroll
    for (int k = 0; k < 9; ++k) { r0[k]=0.f; r1[k]=0.f; r2[k]=0.f; r3[k]=0.f; r4[k]=0.f; }

    // in-flight register sets (slab for a future step)
    float nIA=0.f, nJA=0.f, mIA=0.f, mJA=0.f;  // set A
    float nIB=0.f, nJB=0.f, mIB=0.f, mJB=0.f;  // set B

    // prologue: slab(0) -> buf0 directly; slab(1) -> set A
    {
        int din = d0 - 4;
        bool pv = (din >= 0) && (din < DD);
        float pI=0.f, pJ=0.f, qI=0.f, qJ=0.f;
        const float* Ip = I + (size_t)din * HWN + rowb;
        const float* Jp = J + (size_t)din * HWN + rowb;
        if (pv && vm) { pI = Ip[cm]; pJ = Jp[cm]; }
        if (pv && vh) { qI = Ip[ch]; qJ = Jp[ch]; }
        if (vm) { st[0][0][l] = pI;      st[0][1][l] = pJ; }
        if (vh) { st[0][0][64 + l] = qI; st[0][1][64 + l] = qJ; }
    }
    {
        int din = d0 - 3;                      // slab for s=1
        bool pv = (din >= 0) && (din < DD);
        const float* Ip = I + (size_t)din * HWN + rowb;
        const float* Jp = J + (size_t)din * HWN + rowb;
        if (pv && vm) { nIA = Ip[cm]; nJA = Jp[cm]; }
        if (pv && vh) { mIA = Ip[ch]; mJA = Jp[ch]; }
    }

    for (int bse = 0; bse < 36; bse += 18) {
#pragma unroll
        for (int k = 0; k < 18; ++k) {
            int s = bse + k;
            if (s < NSTEP) {                   // uniform
                const int slot = k % 9;        // compile-time (18%9==0)
                const int buf  = k & 1;        // compile-time (18 even)

                // 1) issue loads for slab s+2 into the free set
                {
                    int din = d0 - 2 + s;      // (d0-4) + (s+2)
                    bool pv = (s + 2 < NSTEP) && (din >= 0) && (din < DD);
                    const float* Ip = I + (size_t)din * HWN + rowb;
                    const float* Jp = J + (size_t)din * HWN + rowb;
                    float tI=0.f,tJ=0.f,uI=0.f,uJ=0.f;
                    if (pv && vm) { tI = Ip[cm]; tJ = Jp[cm]; }
                    if (pv && vh) { uI = Ip[ch]; uJ = Jp[ch]; }
                    if (buf == 0) { nIB=tI; nJB=tJ; mIB=uI; mJB=uJ; }
                    else          { nIA=tI; nJA=tJ; mIA=uI; mJA=uJ; }
                }

                // 2) W-tap from staged slab: window sums of the 5 products
                float a0=0.f,a1=0.f,a2=0.f,a3=0.f,a4=0.f;
#pragma unroll
                for (int j = 0; j < 9; ++j) {
                    float vi = st[buf][0][l + j];
                    float vj = st[buf][1][l + j];
                    a0 += vi;
                    a1 += vj;
                    a2 = fmaf(vi, vi, a2);
                    a3 = fmaf(vj, vj, a3);
                    a4 = fmaf(vi, vj, a4);
                }

                // D-ring (static slot)
                S0 += a0 - r0[slot]; r0[slot] = a0;
                S1 += a1 - r1[slot]; r1[slot] = a1;
                S2 += a2 - r2[slot]; r2[slot] = a2;
                S3 += a3 - r3[slot]; r3[slot] = a3;
                S4 += a4 - r4[slot]; r4[slot] = a4;

                int dc = d0 - 8 + s;           // din - 4
                if (s >= 8) {                  // uniform; dc < d0+DSEG always
                    size_t o = (size_t)(dc - chunk_base) * HWN + rowb
                             + (size_t)(w0 + l);
                    F4[o] = make_float4(S0, S1, S2, S3);
                    F1[o] = S4;
                }

                // 3) stage slab s+1 (loaded at step s-1) into buf^1
                if (buf == 0) {
                    if (vm) { st[1][0][l] = nIA;      st[1][1][l] = nJA; }
                    if (vh) { st[1][0][64 + l] = mIA; st[1][1][64 + l] = mJA; }
                } else {
                    if (vm) { st[0][0][l] = nIB;      st[0][1][l] = nJB; }
                    if (vh) { st[0][0][64 + l] = mIB; st[0][1][64 + l] = mJB; }
                }
            }
        }
    }
}

// ---------------- kB: H-tap (reg ring) + NCC math; no LDS in march --------
// thread owns (d,w), marches h. Packed loads: float4 (S0-S3) + float (S4).
__global__ __launch_bounds__(192) void kB(
    const float4* __restrict__ F4, const float* __restrict__ F1,
    double* __restrict__ partials, int chunk_base, int chunk)
{
    const int drel = blockIdx.x;
    const int hs   = blockIdx.y;
    const int w    = threadIdx.x;
    const int h0   = hs * HS;
    const float4* __restrict__ B4 = F4 + (size_t)drel * HWN + (size_t)w;
    const float*  __restrict__ B1 = F1 + (size_t)drel * HWN + (size_t)w;

    float r0[9], r1[9], r2[9], r3[9], r4[9];
    float S0=0.f,S1=0.f,S2=0.f,S3=0.f,S4=0.f;
#pragma unroll
    for (int k = 0; k < 9; ++k) { r0[k]=0.f; r1[k]=0.f; r2[k]=0.f; r3[k]=0.f; r4[k]=0.f; }

    float acc = 0.f;

    float c0=0.f,c1=0.f,c2=0.f,c3=0.f,c4=0.f;
    {
        int hin = h0 - 4;
        if (hin >= 0) {
            size_t o = (size_t)hin * WW;
            float4 v = B4[o];
            c0=v.x; c1=v.y; c2=v.z; c3=v.w; c4=B1[o];
        }
    }

    for (int bse = 0; bse < 36; bse += 9) {
#pragma unroll
        for (int k = 0; k < 9; ++k) {
            int s = bse + k;

            float n0=0.f,n1=0.f,n2=0.f,n3=0.f,n4=0.f;
            int hin1 = h0 - 3 + s;
            if (s < 35 && hin1 >= 0 && hin1 < HH) {
                size_t o = (size_t)hin1 * WW;
                float4 v = B4[o];
                n0=v.x; n1=v.y; n2=v.z; n3=v.w; n4=B1[o];
            }

            S0 += c0 - r0[k]; r0[k] = c0;
            S1 += c1 - r1[k]; r1[k] = c1;
            S2 += c2 - r2[k]; r2[k] = c2;
            S3 += c3 - r3[k]; r3[k] = c3;
            S4 += c4 - r4[k]; r4[k] = c4;

            if (s >= 8) {
                const float inv = 1.0f / 729.0f;
                float cross = S4 - S0 * S1 * inv;
                float varI  = S2 - S0 * S0 * inv;
                float varJ  = S3 - S1 * S1 * inv;
                acc += cross * cross / (varI * varJ + 1e-5f);
            }

            c0=n0; c1=n1; c2=n2; c3=n3; c4=n4;
        }
    }

    __shared__ float red[192];
    red[w] = acc;
    __syncthreads();
#pragma unroll
    for (int off = 96; off >= 3; off >>= 1) {
        if (w < off) red[w] += red[w + off];
        __syncthreads();
    }
    if (w == 0) {
        int d = chunk_base + drel;
        partials[d * NHS + hs] = (double)(red[0] + red[1] + red[2]);
    }
}

// ---------------- k3: final reduction of 1536 partials --------------------
__global__ __launch_bounds__(256) void k3_reduce(
    const double* __restrict__ partials, float* __restrict__ out)
{
    __shared__ double red[256];
    int t = threadIdx.x;
    double a = 0.0;
    for (int i = t; i < NPART; i += 256) a += partials[i];
    red[t] = a;
    __syncthreads();
    for (int off = 128; off > 0; off >>= 1) {
        if (t < off) red[t] += red[t + off];
        __syncthreads();
    }
    if (t == 0) out[0] = (float)(-red[0] / (double)PLANE);
}

extern "C" void kernel_launch(void* const* d_in, const int* in_sizes, int n_in,
                              void* d_out, int out_size, void* d_ws, size_t ws_size,
                              hipStream_t stream)
{
    const float* I = (const float*)d_in[0];
    const float* J = (const float*)d_in[1];
    float* out = (float*)d_out;

    double* partials = (double*)d_ws;
    const size_t part_bytes = 16384;               // 1536*8 rounded up; 16B align

    // Largest d-chunk (multiple of DSEG=16, divisor of 192) fitting in ws.
    static const int chunks[6] = {192, 96, 64, 48, 32, 16};
    int chunk = 16;
    for (int i = 0; i < 6; ++i) {
        size_t need = part_bytes + 20ull * (size_t)chunks[i] * HWN;  // 16+4 B/voxel
        if (need <= ws_size) { chunk = chunks[i]; break; }
    }

    float4* F4 = (float4*)((char*)d_ws + part_bytes);
    float*  F1 = (float*)((char*)d_ws + part_bytes + 16ull * (size_t)chunk * HWN);

    for (int cb = 0; cb < DD; cb += chunk) {
        kA<<<dim3(HH, chunk / DSEG), dim3(192), 0, stream>>>(I, J, F4, F1, cb, chunk);
        kB<<<dim3(chunk, NHS), dim3(192), 0, stream>>>(F4, F1, partials, cb, chunk);
    }
    k3_reduce<<<dim3(1), dim3(256), 0, stream>>>(partials, out);
}